// Round 2
// baseline (2262.110 us; speedup 1.0000x reference)
//
#include <hip/hip_runtime.h>

#define T_N 4096
#define B_N 64
#define I_N 128
#define H_N 128
#define BH  (B_N * H_N)

// ---------------------------------------------------------------------------
// Phase 1: xp[t,b,:] = x[t,b,:] @ W_ih^T + b_ih -> written into out[0..T*B*H)
// (phase 2 reads it and overwrites with h_t in place).
// Grid: T*B/128 blocks x 256 threads; per block 128 rows x 128 cols.
// Thread (tx=tid&15, ty=tid>>4): 8 rows (ty*8+r) x 8 cols ({tx*4+c} u {64+tx*4+c}).
// Split col-groups keep wt reads at 2-way-max bank aliasing.
// ---------------------------------------------------------------------------
__global__ __launch_bounds__(256) void xproj_kernel(
    const float* __restrict__ x, const float* __restrict__ Wih,
    const float* __restrict__ bih, float* __restrict__ xp)
{
    __shared__ float wt[I_N][H_N];   // wt[k][j] = Wih[j][k], 64 KB
    const int tid = threadIdx.x;

    {
        const float4* w4 = (const float4*)Wih;
        #pragma unroll
        for (int it = 0; it < 16; ++it) {
            int i = tid * 16 + it;          // 0..4095 float4s
            float4 v = w4[i];
            int r = i >> 5;                 // W row j
            int k = (i & 31) << 2;          // k base
            wt[k + 0][r] = v.x;
            wt[k + 1][r] = v.y;
            wt[k + 2][r] = v.z;
            wt[k + 3][r] = v.w;
        }
    }
    __syncthreads();

    const int  tx   = tid & 15;
    const int  ty   = tid >> 4;
    const long row0 = (long)blockIdx.x * 128;
    const float* xbase = x + (row0 + ty * 8) * I_N;

    float acc[8][8];
    #pragma unroll
    for (int r = 0; r < 8; ++r)
        #pragma unroll
        for (int c = 0; c < 8; ++c) acc[r][c] = 0.0f;

    #pragma unroll 2
    for (int k4 = 0; k4 < I_N / 4; ++k4) {
        float4 xv[8];
        #pragma unroll
        for (int r = 0; r < 8; ++r)
            xv[r] = *(const float4*)(xbase + r * I_N + k4 * 4);

        #pragma unroll
        for (int kk = 0; kk < 4; ++kk) {
            int k = k4 * 4 + kk;
            float4 w0 = *(const float4*)&wt[k][tx * 4];
            float4 w1 = *(const float4*)&wt[k][64 + tx * 4];
            #pragma unroll
            for (int r = 0; r < 8; ++r) {
                float xk = (kk == 0) ? xv[r].x : (kk == 1) ? xv[r].y
                         : (kk == 2) ? xv[r].z : xv[r].w;
                acc[r][0] = fmaf(xk, w0.x, acc[r][0]);
                acc[r][1] = fmaf(xk, w0.y, acc[r][1]);
                acc[r][2] = fmaf(xk, w0.z, acc[r][2]);
                acc[r][3] = fmaf(xk, w0.w, acc[r][3]);
                acc[r][4] = fmaf(xk, w1.x, acc[r][4]);
                acc[r][5] = fmaf(xk, w1.y, acc[r][5]);
                acc[r][6] = fmaf(xk, w1.z, acc[r][6]);
                acc[r][7] = fmaf(xk, w1.w, acc[r][7]);
            }
        }
    }

    float4 b0 = *(const float4*)(bih + tx * 4);
    float4 b1 = *(const float4*)(bih + 64 + tx * 4);
    #pragma unroll
    for (int r = 0; r < 8; ++r) {
        long row = row0 + ty * 8 + r;
        float4 o0, o1;
        o0.x = acc[r][0] + b0.x;  o0.y = acc[r][1] + b0.y;
        o0.z = acc[r][2] + b0.z;  o0.w = acc[r][3] + b0.w;
        o1.x = acc[r][4] + b1.x;  o1.y = acc[r][5] + b1.y;
        o1.z = acc[r][6] + b1.z;  o1.w = acc[r][7] + b1.w;
        *(float4*)(xp + row * H_N + tx * 4)      = o0;
        *(float4*)(xp + row * H_N + 64 + tx * 4) = o1;
    }
}

// ---------------------------------------------------------------------------
// Phase 2: sequential scan, one block (one CU) per batch element.
// Thread (p = tid&7, jt = tid>>3): outputs j = 4*jt..4*jt+3, k-slice
// [16p,16p+16). W fragment (64 floats) in VGPRs. h double-buffered in LDS,
// chunk-padded [8][20] so the 8 broadcast addrs/wave tile all 32 banks.
// Partials combined with xor-1/2/4 shuffle butterfly. Raw s_barrier with
// lgkmcnt(0) only -> global h-stores and the 4-step-deep xp prefetch stay
// in flight across steps (no per-step vmcnt(0) drain).
// ---------------------------------------------------------------------------
__device__ __forceinline__ float tanh_fast(float x) {
    float e = __expf(2.0f * x);
    return 1.0f - 2.0f * __builtin_amdgcn_rcpf(e + 1.0f);
}

__global__ __launch_bounds__(256, 1) void scan_kernel(
    const float* __restrict__ Whh, const float* __restrict__ bhh,
    const float* __restrict__ h0, float* __restrict__ out)
{
    const int tid = threadIdx.x;
    const int b   = blockIdx.x;
    const int p   = tid & 7;          // k-chunk: [16p, 16p+16)
    const int jt  = tid >> 3;         // 0..31 ; j = 4*jt + {0..3}
    __shared__ float hbuf[2][8][20];  // [buf][chunk][16 floats + 4 pad]

    // W fragment: w[j][c] = Whh[4jt+j][16p + 4c .. +4)
    float4 w[4][4];
    #pragma unroll
    for (int j = 0; j < 4; ++j)
        #pragma unroll
        for (int c = 0; c < 4; ++c)
            w[j][c] = *(const float4*)(Whh + (4 * jt + j) * H_N + 16 * p + 4 * c);

    const float4 bh4 = *(const float4*)(bhh + 4 * jt);

    if (tid < H_N) hbuf[0][tid >> 4][tid & 15] = h0[b * H_N + tid];

    const float* xq = out + b * H_N + 4 * jt;   // xp (t,b,4jt..) at xq + t*BH
    float*       oq = out + b * H_N + 4 * jt;

    float4 xv[4];
    #pragma unroll
    for (int d = 0; d < 4; ++d)
        xv[d] = *(const float4*)(xq + (size_t)d * BH);

    __syncthreads();

#define FMA_E(C, HE)                                                          \
    a0 = fmaf(w[0][C].HE, hv##C.HE, a0);                                      \
    a1 = fmaf(w[1][C].HE, hv##C.HE, a1);                                      \
    a2 = fmaf(w[2][C].HE, hv##C.HE, a2);                                      \
    a3 = fmaf(w[3][C].HE, hv##C.HE, a3);

#define RNN_STEP(T0, XV, CUR) do {                                            \
        float4 hv0 = *(const float4*)&hbuf[CUR][p][0];                        \
        float4 hv1 = *(const float4*)&hbuf[CUR][p][4];                        \
        float4 hv2 = *(const float4*)&hbuf[CUR][p][8];                        \
        float4 hv3 = *(const float4*)&hbuf[CUR][p][12];                       \
        float a0 = 0.f, a1 = 0.f, a2 = 0.f, a3 = 0.f;                         \
        FMA_E(0, x) FMA_E(0, y) FMA_E(0, z) FMA_E(0, w)                       \
        FMA_E(1, x) FMA_E(1, y) FMA_E(1, z) FMA_E(1, w)                       \
        FMA_E(2, x) FMA_E(2, y) FMA_E(2, z) FMA_E(2, w)                       \
        FMA_E(3, x) FMA_E(3, y) FMA_E(3, z) FMA_E(3, w)                       \
        a0 += __shfl_xor(a0, 1); a1 += __shfl_xor(a1, 1);                     \
        a2 += __shfl_xor(a2, 1); a3 += __shfl_xor(a3, 1);                     \
        a0 += __shfl_xor(a0, 2); a1 += __shfl_xor(a1, 2);                     \
        a2 += __shfl_xor(a2, 2); a3 += __shfl_xor(a3, 2);                     \
        a0 += __shfl_xor(a0, 4); a1 += __shfl_xor(a1, 4);                     \
        a2 += __shfl_xor(a2, 4); a3 += __shfl_xor(a3, 4);                     \
        float4 h4;                                                            \
        h4.x = tanh_fast(a0 + (XV).x + bh4.x);                                \
        h4.y = tanh_fast(a1 + (XV).y + bh4.y);                                \
        h4.z = tanh_fast(a2 + (XV).z + bh4.z);                                \
        h4.w = tanh_fast(a3 + (XV).w + bh4.w);                                \
        if (p == 0) {                                                         \
            *(float4*)&hbuf[(CUR) ^ 1][jt >> 2][(jt & 3) << 2] = h4;          \
            *(float4*)(oq + (size_t)(T0) * BH) = h4;                          \
            if ((T0) == T_N - 1) *(float4*)(oq + (size_t)T_N * BH) = h4;      \
        }                                                                     \
        asm volatile("s_waitcnt lgkmcnt(0)" ::: "memory");                    \
        __builtin_amdgcn_s_barrier();                                         \
        asm volatile("" ::: "memory");                                        \
    } while (0)

    for (int t = 0; t < T_N; t += 4) {
        RNN_STEP(t + 0, xv[0], 0);
        if (t + 4 < T_N) xv[0] = *(const float4*)(xq + (size_t)(t + 4) * BH);
        RNN_STEP(t + 1, xv[1], 1);
        if (t + 5 < T_N) xv[1] = *(const float4*)(xq + (size_t)(t + 5) * BH);
        RNN_STEP(t + 2, xv[2], 0);
        if (t + 6 < T_N) xv[2] = *(const float4*)(xq + (size_t)(t + 6) * BH);
        RNN_STEP(t + 3, xv[3], 1);
        if (t + 7 < T_N) xv[3] = *(const float4*)(xq + (size_t)(t + 7) * BH);
    }
#undef RNN_STEP
#undef FMA_E
}

extern "C" void kernel_launch(void* const* d_in, const int* in_sizes, int n_in,
                              void* d_out, int out_size, void* d_ws, size_t ws_size,
                              hipStream_t stream) {
    const float* x   = (const float*)d_in[0];
    const float* h0  = (const float*)d_in[1];
    const float* Wih = (const float*)d_in[2];
    const float* Whh = (const float*)d_in[3];
    const float* bih = (const float*)d_in[4];
    const float* bhh = (const float*)d_in[5];
    float* out = (float*)d_out;

    xproj_kernel<<<dim3((T_N * B_N) / 128), 256, 0, stream>>>(x, Wih, bih, out);
    scan_kernel<<<dim3(B_N), 256, 0, stream>>>(Whh, bhh, h0, out);
}

// Round 3
// 1997.640 us; speedup vs baseline: 1.1324x; 1.1324x over previous
//
#include <hip/hip_runtime.h>

#define T_N 4096
#define B_N 64
#define I_N 128
#define H_N 128
#define BH  (B_N * H_N)

// ---------------------------------------------------------------------------
// Phase 1: xp[t,b,:] = x[t,b,:] @ W_ih^T + b_ih -> written into out[0..T*B*H)
// (phase 2 reads it and overwrites with h_t in place). Unchanged from R2.
// ---------------------------------------------------------------------------
__global__ __launch_bounds__(256) void xproj_kernel(
    const float* __restrict__ x, const float* __restrict__ Wih,
    const float* __restrict__ bih, float* __restrict__ xp)
{
    __shared__ float wt[I_N][H_N];   // wt[k][j] = Wih[j][k], 64 KB
    const int tid = threadIdx.x;

    {
        const float4* w4 = (const float4*)Wih;
        #pragma unroll
        for (int it = 0; it < 16; ++it) {
            int i = tid * 16 + it;          // 0..4095 float4s
            float4 v = w4[i];
            int r = i >> 5;                 // W row j
            int k = (i & 31) << 2;          // k base
            wt[k + 0][r] = v.x;
            wt[k + 1][r] = v.y;
            wt[k + 2][r] = v.z;
            wt[k + 3][r] = v.w;
        }
    }
    __syncthreads();

    const int  tx   = tid & 15;
    const int  ty   = tid >> 4;
    const long row0 = (long)blockIdx.x * 128;
    const float* xbase = x + (row0 + ty * 8) * I_N;

    float acc[8][8];
    #pragma unroll
    for (int r = 0; r < 8; ++r)
        #pragma unroll
        for (int c = 0; c < 8; ++c) acc[r][c] = 0.0f;

    #pragma unroll 2
    for (int k4 = 0; k4 < I_N / 4; ++k4) {
        float4 xv[8];
        #pragma unroll
        for (int r = 0; r < 8; ++r)
            xv[r] = *(const float4*)(xbase + r * I_N + k4 * 4);

        #pragma unroll
        for (int kk = 0; kk < 4; ++kk) {
            int k = k4 * 4 + kk;
            float4 w0 = *(const float4*)&wt[k][tx * 4];
            float4 w1 = *(const float4*)&wt[k][64 + tx * 4];
            #pragma unroll
            for (int r = 0; r < 8; ++r) {
                float xk = (kk == 0) ? xv[r].x : (kk == 1) ? xv[r].y
                         : (kk == 2) ? xv[r].z : xv[r].w;
                acc[r][0] = fmaf(xk, w0.x, acc[r][0]);
                acc[r][1] = fmaf(xk, w0.y, acc[r][1]);
                acc[r][2] = fmaf(xk, w0.z, acc[r][2]);
                acc[r][3] = fmaf(xk, w0.w, acc[r][3]);
                acc[r][4] = fmaf(xk, w1.x, acc[r][4]);
                acc[r][5] = fmaf(xk, w1.y, acc[r][5]);
                acc[r][6] = fmaf(xk, w1.z, acc[r][6]);
                acc[r][7] = fmaf(xk, w1.w, acc[r][7]);
            }
        }
    }

    float4 b0 = *(const float4*)(bih + tx * 4);
    float4 b1 = *(const float4*)(bih + 64 + tx * 4);
    #pragma unroll
    for (int r = 0; r < 8; ++r) {
        long row = row0 + ty * 8 + r;
        float4 o0, o1;
        o0.x = acc[r][0] + b0.x;  o0.y = acc[r][1] + b0.y;
        o0.z = acc[r][2] + b0.z;  o0.w = acc[r][3] + b0.w;
        o1.x = acc[r][4] + b1.x;  o1.y = acc[r][5] + b1.y;
        o1.z = acc[r][6] + b1.z;  o1.w = acc[r][7] + b1.w;
        *(float4*)(xp + row * H_N + tx * 4)      = o0;
        *(float4*)(xp + row * H_N + 64 + tx * 4) = o1;
    }
}

// ---------------------------------------------------------------------------
// Phase 2: sequential scan, one block (one CU) per batch element.
// k-split lanes chosen as lane-bits {0,1,3} so the 8-way partial reduce is
// 3 DPP VALU rounds (xor1 quad_perm, xor2 quad_perm, xor8 row_ror:8) --
// ~4 cyc each instead of ~90-cyc ds_bpermute round-trips.
//   lane l:  p  = (l&3) | ((l>>1)&4)      k-slice [16p, 16p+16)
//            jt = ((l>>2)&1) | ((l>>4)<<1)  + 8*wave   -> outputs 4jt..4jt+3
// h double-buffered in LDS, chunk-padded [8][20] (conflict-free, verified
// R2: SQ_LDS_BANK_CONFLICT ~ 0). Raw s_barrier + lgkmcnt(0); global h-store
// and 4-deep xp prefetch stay in flight.
// ---------------------------------------------------------------------------
__device__ __forceinline__ float tanh_fast(float x) {
    float e = __expf(2.0f * x);
    return 1.0f - 2.0f * __builtin_amdgcn_rcpf(e + 1.0f);
}

#define DPP_XOR1 0xB1   // quad_perm [1,0,3,2]
#define DPP_XOR2 0x4E   // quad_perm [2,3,0,1]
#define DPP_XOR8 0x128  // row_ror:8  (== xor8 within a 16-lane row)

__device__ __forceinline__ float dpp_add(float v, const int ctrl) {
    int s = __float_as_int(v);
    int r;
    switch (ctrl) {  // ctrl must be compile-time; switch keeps it literal
        case DPP_XOR1: r = __builtin_amdgcn_update_dpp(0, s, DPP_XOR1, 0xF, 0xF, true); break;
        case DPP_XOR2: r = __builtin_amdgcn_update_dpp(0, s, DPP_XOR2, 0xF, 0xF, true); break;
        default:       r = __builtin_amdgcn_update_dpp(0, s, DPP_XOR8, 0xF, 0xF, true); break;
    }
    return v + __int_as_float(r);
}

__global__ __launch_bounds__(256, 1) void scan_kernel(
    const float* __restrict__ Whh, const float* __restrict__ bhh,
    const float* __restrict__ h0, float* __restrict__ out)
{
    const int tid  = threadIdx.x;
    const int b    = blockIdx.x;
    const int lane = tid & 63;
    const int wv   = tid >> 6;
    const int p    = (lane & 3) | ((lane >> 1) & 4);          // 0..7
    const int jt   = (((lane >> 2) & 1) | ((lane >> 4) << 1)) + wv * 8;  // 0..31
    __shared__ float hbuf[2][8][20];  // [buf][chunk][16 floats + 4 pad]

    // W fragment: w[j][c] = Whh[4jt+j][16p + 4c .. +4)
    float4 w[4][4];
    #pragma unroll
    for (int j = 0; j < 4; ++j)
        #pragma unroll
        for (int c = 0; c < 4; ++c)
            w[j][c] = *(const float4*)(Whh + (4 * jt + j) * H_N + 16 * p + 4 * c);

    const float4 bh4 = *(const float4*)(bhh + 4 * jt);

    if (tid < H_N) hbuf[0][tid >> 4][tid & 15] = h0[b * H_N + tid];

    const float* xq = out + b * H_N + 4 * jt;   // xp (t,b,4jt..) at xq + t*BH
    float*       oq = out + b * H_N + 4 * jt;

    float4 xv[4];
    #pragma unroll
    for (int d = 0; d < 4; ++d)
        xv[d] = *(const float4*)(xq + (size_t)d * BH);

    __syncthreads();

#define FMA_E(C, HE)                                                          \
    a0 = fmaf(w[0][C].HE, hv##C.HE, a0);                                      \
    a1 = fmaf(w[1][C].HE, hv##C.HE, a1);                                      \
    a2 = fmaf(w[2][C].HE, hv##C.HE, a2);                                      \
    a3 = fmaf(w[3][C].HE, hv##C.HE, a3);

#define RNN_STEP(T0, XV, CUR) do {                                            \
        float4 hv0 = *(const float4*)&hbuf[CUR][p][0];                        \
        float4 hv1 = *(const float4*)&hbuf[CUR][p][4];                        \
        float4 hv2 = *(const float4*)&hbuf[CUR][p][8];                        \
        float4 hv3 = *(const float4*)&hbuf[CUR][p][12];                       \
        float a0 = 0.f, a1 = 0.f, a2 = 0.f, a3 = 0.f;                         \
        FMA_E(0, x) FMA_E(0, y) FMA_E(0, z) FMA_E(0, w)                       \
        FMA_E(1, x) FMA_E(1, y) FMA_E(1, z) FMA_E(1, w)                       \
        FMA_E(2, x) FMA_E(2, y) FMA_E(2, z) FMA_E(2, w)                       \
        FMA_E(3, x) FMA_E(3, y) FMA_E(3, z) FMA_E(3, w)                       \
        a0 = dpp_add(a0, DPP_XOR1); a1 = dpp_add(a1, DPP_XOR1);               \
        a2 = dpp_add(a2, DPP_XOR1); a3 = dpp_add(a3, DPP_XOR1);               \
        a0 = dpp_add(a0, DPP_XOR2); a1 = dpp_add(a1, DPP_XOR2);               \
        a2 = dpp_add(a2, DPP_XOR2); a3 = dpp_add(a3, DPP_XOR2);               \
        a0 = dpp_add(a0, DPP_XOR8); a1 = dpp_add(a1, DPP_XOR8);               \
        a2 = dpp_add(a2, DPP_XOR8); a3 = dpp_add(a3, DPP_XOR8);               \
        float4 h4;                                                            \
        h4.x = tanh_fast(a0 + (XV).x + bh4.x);                                \
        h4.y = tanh_fast(a1 + (XV).y + bh4.y);                                \
        h4.z = tanh_fast(a2 + (XV).z + bh4.z);                                \
        h4.w = tanh_fast(a3 + (XV).w + bh4.w);                                \
        if (p == 0) {                                                         \
            *(float4*)&hbuf[(CUR) ^ 1][jt >> 2][(jt & 3) << 2] = h4;          \
            *(float4*)(oq + (size_t)(T0) * BH) = h4;                          \
            if ((T0) == T_N - 1) *(float4*)(oq + (size_t)T_N * BH) = h4;      \
        }                                                                     \
        asm volatile("s_waitcnt lgkmcnt(0)" ::: "memory");                    \
        __builtin_amdgcn_s_barrier();                                         \
        asm volatile("" ::: "memory");                                        \
    } while (0)

    for (int t = 0; t < T_N; t += 4) {
        RNN_STEP(t + 0, xv[0], 0);
        if (t + 4 < T_N) xv[0] = *(const float4*)(xq + (size_t)(t + 4) * BH);
        RNN_STEP(t + 1, xv[1], 1);
        if (t + 5 < T_N) xv[1] = *(const float4*)(xq + (size_t)(t + 5) * BH);
        RNN_STEP(t + 2, xv[2], 0);
        if (t + 6 < T_N) xv[2] = *(const float4*)(xq + (size_t)(t + 6) * BH);
        RNN_STEP(t + 3, xv[3], 1);
        if (t + 7 < T_N) xv[3] = *(const float4*)(xq + (size_t)(t + 7) * BH);
    }
#undef RNN_STEP
#undef FMA_E
}

extern "C" void kernel_launch(void* const* d_in, const int* in_sizes, int n_in,
                              void* d_out, int out_size, void* d_ws, size_t ws_size,
                              hipStream_t stream) {
    const float* x   = (const float*)d_in[0];
    const float* h0  = (const float*)d_in[1];
    const float* Wih = (const float*)d_in[2];
    const float* Whh = (const float*)d_in[3];
    const float* bih = (const float*)d_in[4];
    const float* bhh = (const float*)d_in[5];
    float* out = (float*)d_out;

    xproj_kernel<<<dim3((T_N * B_N) / 128), 256, 0, stream>>>(x, Wih, bih, out);
    scan_kernel<<<dim3(B_N), 256, 0, stream>>>(Whh, bhh, h0, out);
}

// Round 4
// 1955.000 us; speedup vs baseline: 1.1571x; 1.0218x over previous
//
#include <hip/hip_runtime.h>

#define T_N 4096
#define B_N 64
#define I_N 128
#define H_N 128
#define BH  (B_N * H_N)

// ---------------------------------------------------------------------------
// Phase 1: xp[t,b,:] = x[t,b,:] @ W_ih^T + b_ih -> written into out[0..T*B*H)
// (phase 2 reads it and overwrites with h_t in place). Unchanged from R2/R3.
// ---------------------------------------------------------------------------
__global__ __launch_bounds__(256) void xproj_kernel(
    const float* __restrict__ x, const float* __restrict__ Wih,
    const float* __restrict__ bih, float* __restrict__ xp)
{
    __shared__ float wt[I_N][H_N];   // wt[k][j] = Wih[j][k], 64 KB
    const int tid = threadIdx.x;

    {
        const float4* w4 = (const float4*)Wih;
        #pragma unroll
        for (int it = 0; it < 16; ++it) {
            int i = tid * 16 + it;          // 0..4095 float4s
            float4 v = w4[i];
            int r = i >> 5;                 // W row j
            int k = (i & 31) << 2;          // k base
            wt[k + 0][r] = v.x;
            wt[k + 1][r] = v.y;
            wt[k + 2][r] = v.z;
            wt[k + 3][r] = v.w;
        }
    }
    __syncthreads();

    const int  tx   = tid & 15;
    const int  ty   = tid >> 4;
    const long row0 = (long)blockIdx.x * 128;
    const float* xbase = x + (row0 + ty * 8) * I_N;

    float acc[8][8];
    #pragma unroll
    for (int r = 0; r < 8; ++r)
        #pragma unroll
        for (int c = 0; c < 8; ++c) acc[r][c] = 0.0f;

    #pragma unroll 2
    for (int k4 = 0; k4 < I_N / 4; ++k4) {
        float4 xv[8];
        #pragma unroll
        for (int r = 0; r < 8; ++r)
            xv[r] = *(const float4*)(xbase + r * I_N + k4 * 4);

        #pragma unroll
        for (int kk = 0; kk < 4; ++kk) {
            int k = k4 * 4 + kk;
            float4 w0 = *(const float4*)&wt[k][tx * 4];
            float4 w1 = *(const float4*)&wt[k][64 + tx * 4];
            #pragma unroll
            for (int r = 0; r < 8; ++r) {
                float xk = (kk == 0) ? xv[r].x : (kk == 1) ? xv[r].y
                         : (kk == 2) ? xv[r].z : xv[r].w;
                acc[r][0] = fmaf(xk, w0.x, acc[r][0]);
                acc[r][1] = fmaf(xk, w0.y, acc[r][1]);
                acc[r][2] = fmaf(xk, w0.z, acc[r][2]);
                acc[r][3] = fmaf(xk, w0.w, acc[r][3]);
                acc[r][4] = fmaf(xk, w1.x, acc[r][4]);
                acc[r][5] = fmaf(xk, w1.y, acc[r][5]);
                acc[r][6] = fmaf(xk, w1.z, acc[r][6]);
                acc[r][7] = fmaf(xk, w1.w, acc[r][7]);
            }
        }
    }

    float4 b0 = *(const float4*)(bih + tx * 4);
    float4 b1 = *(const float4*)(bih + 64 + tx * 4);
    #pragma unroll
    for (int r = 0; r < 8; ++r) {
        long row = row0 + ty * 8 + r;
        float4 o0, o1;
        o0.x = acc[r][0] + b0.x;  o0.y = acc[r][1] + b0.y;
        o0.z = acc[r][2] + b0.z;  o0.w = acc[r][3] + b0.w;
        o1.x = acc[r][4] + b1.x;  o1.y = acc[r][5] + b1.y;
        o1.z = acc[r][6] + b1.z;  o1.w = acc[r][7] + b1.w;
        *(float4*)(xp + row * H_N + tx * 4)      = o0;
        *(float4*)(xp + row * H_N + 64 + tx * 4) = o1;
    }
}

// ---------------------------------------------------------------------------
// Phase 2: sequential scan, one block (one CU) per batch element.
// R3 layout kept: lane l -> p = (l&3)|((l>>1)&4) (k-slice [16p,16p+16)),
// jt = ((l>>2)&1)|((l>>4)<<1) + 8*wave (outputs 4jt..4jt+3); DPP xor1/xor2/
// xor8 reduce; padded hbuf[2][8][20]; raw s_barrier + lgkmcnt(0) only.
// R4 deltas (serial-chain shortening):
//  - FMA chains depth 16 -> 4: 16 accumulators (4 out x 4 chunks of DOT4)
//    + 2-level tree add.
//  - tanh via Pade[5/4] + med3 clamp (no exp; single rcp; err <= ~1e-3).
//  - global h-store moved AFTER the barrier (off the pre-barrier path).
//  - xv+bh prefolded while LDS reads are in flight.
// ---------------------------------------------------------------------------
__device__ __forceinline__ float tanh_pade(float x) {
    float u = x * x;
    float n = fmaf(u, u + 105.0f, 945.0f);              // u^2 + 105u + 945
    float d = fmaf(u, fmaf(15.0f, u, 420.0f), 945.0f);  // 15u^2 + 420u + 945
    float t = x * n * __builtin_amdgcn_rcpf(d);
    return fminf(1.0f, fmaxf(-1.0f, t));                // v_med3_f32
}

#define DPP_XOR1 0xB1   // quad_perm [1,0,3,2]
#define DPP_XOR2 0x4E   // quad_perm [2,3,0,1]
#define DPP_XOR8 0x128  // row_ror:8  (== xor8 within a 16-lane row)

__device__ __forceinline__ float dpp_add(float v, const int ctrl) {
    int s = __float_as_int(v);
    int r;
    switch (ctrl) {  // ctrl must be compile-time; switch keeps it literal
        case DPP_XOR1: r = __builtin_amdgcn_update_dpp(0, s, DPP_XOR1, 0xF, 0xF, true); break;
        case DPP_XOR2: r = __builtin_amdgcn_update_dpp(0, s, DPP_XOR2, 0xF, 0xF, true); break;
        default:       r = __builtin_amdgcn_update_dpp(0, s, DPP_XOR8, 0xF, 0xF, true); break;
    }
    return v + __int_as_float(r);
}

#define DOT4(W4, H4)                                                          \
    fmaf((W4).x, (H4).x, fmaf((W4).y, (H4).y,                                 \
    fmaf((W4).z, (H4).z, (W4).w * (H4).w)))

__global__ __launch_bounds__(256, 1) void scan_kernel(
    const float* __restrict__ Whh, const float* __restrict__ bhh,
    const float* __restrict__ h0, float* __restrict__ out)
{
    const int tid  = threadIdx.x;
    const int b    = blockIdx.x;
    const int lane = tid & 63;
    const int wv   = tid >> 6;
    const int p    = (lane & 3) | ((lane >> 1) & 4);          // 0..7
    const int jt   = (((lane >> 2) & 1) | ((lane >> 4) << 1)) + wv * 8;  // 0..31
    __shared__ float hbuf[2][8][20];  // [buf][chunk][16 floats + 4 pad]

    // W fragment: w[j][c] = Whh[4jt+j][16p + 4c .. +4)
    float4 w[4][4];
    #pragma unroll
    for (int j = 0; j < 4; ++j)
        #pragma unroll
        for (int c = 0; c < 4; ++c)
            w[j][c] = *(const float4*)(Whh + (4 * jt + j) * H_N + 16 * p + 4 * c);

    const float4 bh4 = *(const float4*)(bhh + 4 * jt);

    if (tid < H_N) hbuf[0][tid >> 4][tid & 15] = h0[b * H_N + tid];

    const float* xq = out + b * H_N + 4 * jt;   // xp (t,b,4jt..) at xq + t*BH
    float*       oq = out + b * H_N + 4 * jt;

    float4 xv[4];
    #pragma unroll
    for (int d = 0; d < 4; ++d)
        xv[d] = *(const float4*)(xq + (size_t)d * BH);

    __syncthreads();

#define RNN_STEP(T0, XV, CUR) do {                                            \
        float4 hv0 = *(const float4*)&hbuf[CUR][p][0];                        \
        float4 hv1 = *(const float4*)&hbuf[CUR][p][4];                        \
        float4 hv2 = *(const float4*)&hbuf[CUR][p][8];                        \
        float4 hv3 = *(const float4*)&hbuf[CUR][p][12];                       \
        float4 xvbh;                                                          \
        xvbh.x = (XV).x + bh4.x; xvbh.y = (XV).y + bh4.y;                     \
        xvbh.z = (XV).z + bh4.z; xvbh.w = (XV).w + bh4.w;                     \
        float s0 = (DOT4(w[0][0], hv0) + DOT4(w[0][1], hv1))                  \
                 + (DOT4(w[0][2], hv2) + DOT4(w[0][3], hv3));                 \
        float s1 = (DOT4(w[1][0], hv0) + DOT4(w[1][1], hv1))                  \
                 + (DOT4(w[1][2], hv2) + DOT4(w[1][3], hv3));                 \
        float s2 = (DOT4(w[2][0], hv0) + DOT4(w[2][1], hv1))                  \
                 + (DOT4(w[2][2], hv2) + DOT4(w[2][3], hv3));                 \
        float s3 = (DOT4(w[3][0], hv0) + DOT4(w[3][1], hv1))                  \
                 + (DOT4(w[3][2], hv2) + DOT4(w[3][3], hv3));                 \
        s0 = dpp_add(s0, DPP_XOR1); s1 = dpp_add(s1, DPP_XOR1);               \
        s2 = dpp_add(s2, DPP_XOR1); s3 = dpp_add(s3, DPP_XOR1);               \
        s0 = dpp_add(s0, DPP_XOR2); s1 = dpp_add(s1, DPP_XOR2);               \
        s2 = dpp_add(s2, DPP_XOR2); s3 = dpp_add(s3, DPP_XOR2);               \
        s0 = dpp_add(s0, DPP_XOR8); s1 = dpp_add(s1, DPP_XOR8);               \
        s2 = dpp_add(s2, DPP_XOR8); s3 = dpp_add(s3, DPP_XOR8);               \
        float4 h4;                                                            \
        h4.x = tanh_pade(s0 + xvbh.x);                                        \
        h4.y = tanh_pade(s1 + xvbh.y);                                        \
        h4.z = tanh_pade(s2 + xvbh.z);                                        \
        h4.w = tanh_pade(s3 + xvbh.w);                                        \
        if (p == 0)                                                           \
            *(float4*)&hbuf[(CUR) ^ 1][jt >> 2][(jt & 3) << 2] = h4;          \
        asm volatile("s_waitcnt lgkmcnt(0)" ::: "memory");                    \
        __builtin_amdgcn_s_barrier();                                         \
        if (p == 0) {                                                         \
            *(float4*)(oq + (size_t)(T0) * BH) = h4;                          \
            if ((T0) == T_N - 1) *(float4*)(oq + (size_t)T_N * BH) = h4;      \
        }                                                                     \
        asm volatile("" ::: "memory");                                        \
    } while (0)

    for (int t = 0; t < T_N; t += 4) {
        RNN_STEP(t + 0, xv[0], 0);
        if (t + 4 < T_N) xv[0] = *(const float4*)(xq + (size_t)(t + 4) * BH);
        RNN_STEP(t + 1, xv[1], 1);
        if (t + 5 < T_N) xv[1] = *(const float4*)(xq + (size_t)(t + 5) * BH);
        RNN_STEP(t + 2, xv[2], 0);
        if (t + 6 < T_N) xv[2] = *(const float4*)(xq + (size_t)(t + 6) * BH);
        RNN_STEP(t + 3, xv[3], 1);
        if (t + 7 < T_N) xv[3] = *(const float4*)(xq + (size_t)(t + 7) * BH);
    }
#undef RNN_STEP
}

extern "C" void kernel_launch(void* const* d_in, const int* in_sizes, int n_in,
                              void* d_out, int out_size, void* d_ws, size_t ws_size,
                              hipStream_t stream) {
    const float* x   = (const float*)d_in[0];
    const float* h0  = (const float*)d_in[1];
    const float* Wih = (const float*)d_in[2];
    const float* Whh = (const float*)d_in[3];
    const float* bih = (const float*)d_in[4];
    const float* bhh = (const float*)d_in[5];
    float* out = (float*)d_out;

    xproj_kernel<<<dim3((T_N * B_N) / 128), 256, 0, stream>>>(x, Wih, bih, out);
    scan_kernel<<<dim3(B_N), 256, 0, stream>>>(Whh, bhh, h0, out);
}